// Round 12
// baseline (184.189 us; speedup 1.0000x reference)
//
#include <hip/hip_runtime.h>
#include <hip/hip_bf16.h>
#include <stdint.h>

#define NB 4
#define NN 4096

using f16x8 = __attribute__((ext_vector_type(8))) _Float16;
using f32x4 = __attribute__((ext_vector_type(4))) float;

__device__ __forceinline__ float wave_sum(float v) {
  #pragma unroll
  for (int o = 32; o > 0; o >>= 1) v += __shfl_xor(v, o, 64);
  return v;
}
__device__ __forceinline__ float h2f_bits(unsigned hb) {
  unsigned short us = (unsigned short)hb;
  _Float16 hf;
  __builtin_memcpy(&hf, &us, 2);
  return (float)hf;
}
__device__ __forceinline__ unsigned short f2h_bits(float f) {
  _Float16 hf = (_Float16)f;
  unsigned short us;
  __builtin_memcpy(&us, &hf, 2);
  return us;
}
__device__ __forceinline__ unsigned pack2h(float lo, float hi) {
  return ((unsigned)f2h_bits(hi) << 16) | (unsigned)f2h_bits(lo);
}

// 16-deep branchless sorted-insert cascade (desc). c is clobbered.
#define INS16(c) do { unsigned t_;                      \
  t_ = max(l0, c);  c = min(l0, c);  l0 = t_;           \
  t_ = max(l1, c);  c = min(l1, c);  l1 = t_;           \
  t_ = max(l2, c);  c = min(l2, c);  l2 = t_;           \
  t_ = max(l3, c);  c = min(l3, c);  l3 = t_;           \
  t_ = max(l4, c);  c = min(l4, c);  l4 = t_;           \
  t_ = max(l5, c);  c = min(l5, c);  l5 = t_;           \
  t_ = max(l6, c);  c = min(l6, c);  l6 = t_;           \
  t_ = max(l7, c);  c = min(l7, c);  l7 = t_;           \
  t_ = max(l8, c);  c = min(l8, c);  l8 = t_;           \
  t_ = max(l9, c);  c = min(l9, c);  l9 = t_;           \
  t_ = max(l10, c); c = min(l10, c); l10 = t_;          \
  t_ = max(l11, c); c = min(l11, c); l11 = t_;          \
  t_ = max(l12, c); c = min(l12, c); l12 = t_;          \
  t_ = max(l13, c); c = min(l13, c); l13 = t_;          \
  t_ = max(l14, c); c = min(l14, c); l14 = t_;          \
  l15 = max(l15, c);                                    \
} while (0)

#define SHIFT_L() do { l0=l1; l1=l2; l2=l3; l3=l4; l4=l5; l5=l6; l6=l7; l7=l8; \
  l8=l9; l9=l10; l10=l11; l11=l12; l12=l13; l13=l14; l14=l15; l15=0; } while (0)
#define SHIFT_P() do { p0=p1; p1=p2; p2=p3; p3=p4; p4=p5; p5=p6; p6=p7; p7=p8; \
  p8=p9; p9=p10; p10=p11; p11=p12; p12=p13; p13=p14; p14=p15; p15=0; } while (0)

// ---- k_prepw: fused weight transpose+fp16 pack (w1 and w2), swizzled ---------
__global__ __launch_bounds__(128) void k_prepw(
    const float* __restrict__ w1, const float* __restrict__ w2,
    _Float16* __restrict__ w1t16, _Float16* __restrict__ w2t16) {
  int n = blockIdx.x;
  int t = threadIdx.x;
  __shared__ _Float16 v16[128];
  __shared__ float v[384];
  v16[t] = (_Float16)w1[(size_t)t * 128 + n];
  #pragma unroll
  for (int i = 0; i < 3; ++i) v[i * 128 + t] = w2[(size_t)(i * 128 + t) * 128 + n];
  __syncthreads();
  if (t < 16) {
    union { _Float16 hh[8]; uint4 u; } pk;
    #pragma unroll
    for (int j = 0; j < 8; ++j) pk.hh[j] = v16[t * 8 + j];
    *(uint4*)(w1t16 + (size_t)n * 128 + (size_t)(t ^ (n & 7)) * 8) = pk.u;
  }
  if (t < 48) {
    int kc = t >> 4, cl = t & 15;
    union { _Float16 hh[8]; uint4 u; } pk;
    #pragma unroll
    for (int e = 0; e < 8; ++e) pk.hh[e] = (_Float16)v[t * 8 + e];
    *(uint4*)(w2t16 + (size_t)n * 384 + kc * 128 + (size_t)(cl ^ (n & 7)) * 8) = pk.u;
  }
}

// ---- k1_mfma (FUSED LN): LN(x) in-register -> As (LDS, swizzled fp16);
//      h = GELU(ln @ w1 + b1); writes h16 + hn16 (normalized). ----------------
__global__ __launch_bounds__(256) void k1_mfma(
    const float* __restrict__ x, const float* __restrict__ ln_g,
    const float* __restrict__ ln_b, const _Float16* __restrict__ w1t16,
    const float* __restrict__ b1, _Float16* __restrict__ h16,
    _Float16* __restrict__ hn16) {
  __shared__ _Float16 As[64 * 128];
  __shared__ _Float16 Bs[128 * 128];
  int tid = threadIdx.x;
  int lane = tid & 63;
  int wv = tid >> 6;
  int rbase = blockIdx.x * 64;
  #pragma unroll
  for (int i = 0; i < 8; ++i) {
    int idx = tid + 256 * i;
    __builtin_amdgcn_global_load_lds(
        (const __attribute__((address_space(1))) void*)(w1t16 + (size_t)idx * 8),
        (__attribute__((address_space(3))) void*)(Bs + (size_t)idx * 8), 16, 0, 0);
  }
  // ---- in-register LayerNorm: 4 lanes per row, 32 elems/lane ----
  int r = wv * 16 + (lane >> 2);   // local row
  int q = lane & 3;                // quad within row
  const float4* xr = (const float4*)(x + (size_t)(rbase + r) * 128 + q * 32);
  float4 xv[8];
  #pragma unroll
  for (int j = 0; j < 8; ++j) xv[j] = xr[j];
  float s = 0.f;
  #pragma unroll
  for (int j = 0; j < 8; ++j) s += xv[j].x + xv[j].y + xv[j].z + xv[j].w;
  s += __shfl_xor(s, 1, 64);
  s += __shfl_xor(s, 2, 64);
  float mu = s * (1.0f / 128.0f);
  float vs = 0.f;
  #pragma unroll
  for (int j = 0; j < 8; ++j) {
    float dx_ = xv[j].x - mu, dy_ = xv[j].y - mu, dz_ = xv[j].z - mu, dw_ = xv[j].w - mu;
    vs += dx_ * dx_ + dy_ * dy_ + dz_ * dz_ + dw_ * dw_;
  }
  vs += __shfl_xor(vs, 1, 64);
  vs += __shfl_xor(vs, 2, 64);
  float ri = 1.0f / sqrtf(vs * (1.0f / 128.0f) + 1e-5f);
  const float4* gr = (const float4*)(ln_g + q * 32);
  const float4* br = (const float4*)(ln_b + q * 32);
  #pragma unroll
  for (int cc = 0; cc < 4; ++cc) {
    float4 a0 = xv[cc * 2], a1 = xv[cc * 2 + 1];
    float4 g0 = gr[cc * 2], g1 = gr[cc * 2 + 1];
    float4 bb0 = br[cc * 2], bb1 = br[cc * 2 + 1];
    union { _Float16 hh[8]; uint4 u; } pk;
    pk.hh[0] = (_Float16)((a0.x - mu) * ri * g0.x + bb0.x);
    pk.hh[1] = (_Float16)((a0.y - mu) * ri * g0.y + bb0.y);
    pk.hh[2] = (_Float16)((a0.z - mu) * ri * g0.z + bb0.z);
    pk.hh[3] = (_Float16)((a0.w - mu) * ri * g0.w + bb0.w);
    pk.hh[4] = (_Float16)((a1.x - mu) * ri * g1.x + bb1.x);
    pk.hh[5] = (_Float16)((a1.y - mu) * ri * g1.y + bb1.y);
    pk.hh[6] = (_Float16)((a1.z - mu) * ri * g1.z + bb1.z);
    pk.hh[7] = (_Float16)((a1.w - mu) * ri * g1.w + bb1.w);
    int c = q * 4 + cc;
    *(uint4*)(&As[r * 128 + ((c ^ (r & 7)) << 3)]) = pk.u;
  }
  asm volatile("s_waitcnt vmcnt(0)" ::: "memory");
  __syncthreads();

  int rl = lane & 15, kg = lane >> 4;
  f32x4 acc[8];
  #pragma unroll
  for (int j = 0; j < 8; ++j) acc[j] = (f32x4){0.f, 0.f, 0.f, 0.f};
  #pragma unroll
  for (int kk = 0; kk < 4; ++kk) {
    int cL = kk * 4 + kg;
    int rr = wv * 16 + rl;
    f16x8 a = *(const f16x8*)(As + rr * 128 + (cL ^ (rr & 7)) * 8);
    #pragma unroll
    for (int j = 0; j < 8; ++j) {
      int n = j * 16 + rl;
      f16x8 bf = *(const f16x8*)(Bs + n * 128 + (cL ^ (n & 7)) * 8);
      acc[j] = __builtin_amdgcn_mfma_f32_16x16x32_f16(a, bf, acc[j], 0, 0, 0);
    }
  }
  float ssq[4] = {0.f, 0.f, 0.f, 0.f};
  #pragma unroll
  for (int j = 0; j < 8; ++j) {
    float bv = b1[j * 16 + rl];
    #pragma unroll
    for (int rg = 0; rg < 4; ++rg) {
      float z = acc[j][rg] + bv;
      float g = 0.5f * z * (1.0f + erff(z * 0.70710678118654752440f));
      acc[j][rg] = g;
      ssq[rg] += g * g;
    }
  }
  #pragma unroll
  for (int o = 1; o < 16; o <<= 1)
    #pragma unroll
    for (int rg = 0; rg < 4; ++rg) ssq[rg] += __shfl_xor(ssq[rg], o, 64);
  float rinv[4];
  #pragma unroll
  for (int rg = 0; rg < 4; ++rg) rinv[rg] = 1.0f / fmaxf(sqrtf(ssq[rg]), 1e-12f);

  #pragma unroll
  for (int j = 0; j < 8; ++j) {
    #pragma unroll
    for (int rg = 0; rg < 4; ++rg) {
      float g = acc[j][rg];
      float gp = __shfl_xor(g, 1, 64);
      if ((rl & 1) == 0) {
        int row = rbase + wv * 16 + kg * 4 + rg;
        int col = j * 16 + rl;
        int c = col >> 3;
        int ad = row * 128 + (((c ^ (row & 7))) << 3) + (col & 7);
        *(unsigned*)(h16 + ad) = pack2h(g, gp);
        *(unsigned*)(hn16 + ad) = pack2h(g * rinv[rg], gp * rinv[rg]);
      }
    }
  }
}

// ---- k_scores_topk v7: R11 structure; ballot-terminated prefetched drain,
//      gate update only when an insert happened. ------------------------------
__global__ __launch_bounds__(512, 1) void k_scores_topk(
    const _Float16* __restrict__ hn16, int* __restrict__ nidx,
    float* __restrict__ nval, float* __restrict__ dm12,
    const float* __restrict__ p_log_tau) {
  __shared__ _Float16 Qs[64 * 128];         // 16 KB
  __shared__ _Float16 Cs[2][2][64 * 128];   // 64 KB: [group][dbuf]
  __shared__ unsigned stk[16 * 512];        // 32 KB: stacks, then merge buffer
  int tid = threadIdx.x;
  int lane = tid & 63;
  int wv = tid >> 6;            // 0..7
  int g = wv >> 2;              // m-half
  int wq = wv & 3;
  int rl = lane & 15, kg = lane >> 4;
  int t = tid & 255;            // group-local tid
  int blk = blockIdx.x;
  int b = blk >> 6;
  int qbase = (blk & 63) * 64;
  const _Float16* hb = hn16 + (size_t)b * NN * 128;

  #pragma unroll
  for (int i = 0; i < 2; ++i) {
    int idx = tid + 512 * i;
    __builtin_amdgcn_global_load_lds(
        (const __attribute__((address_space(1))) void*)(hb + (size_t)qbase * 128 + (size_t)idx * 8),
        (__attribute__((address_space(3))) void*)(Qs + (size_t)idx * 8), 16, 0, 0);
  }
  const _Float16* cw = hb + (size_t)(g * 2048) * 128;
  #pragma unroll
  for (int i = 0; i < 4; ++i) {
    int idx = t + 256 * i;
    __builtin_amdgcn_global_load_lds(
        (const __attribute__((address_space(1))) void*)(cw + (size_t)idx * 8),
        (__attribute__((address_space(3))) void*)(&Cs[g][0][0] + (size_t)idx * 8), 16, 0, 0);
  }
  asm volatile("s_waitcnt vmcnt(0)" ::: "memory");
  __syncthreads();

  int qrow = wq * 16 + rl;
  f16x8 bq[4];
  #pragma unroll
  for (int kk = 0; kk < 4; ++kk)
    bq[kk] = *(const f16x8*)(Qs + qrow * 128 + ((kk * 4 + kg) ^ (qrow & 7)) * 8);

  unsigned l0 = 0, l1 = 0, l2 = 0, l3 = 0, l4 = 0, l5 = 0, l6 = 0, l7 = 0,
           l8 = 0, l9 = 0, l10 = 0, l11 = 0, l12 = 0, l13 = 0, l14 = 0, l15 = 0;
  unsigned gate = 0;

  for (int cb = 0; cb < 32; ++cb) {
    int cur = cb & 1;
    if (cb < 31) {  // prefetch next private-group tile
      const _Float16* csrc = cw + (size_t)(cb + 1) * 64 * 128;
      #pragma unroll
      for (int i = 0; i < 4; ++i) {
        int idx = t + 256 * i;
        __builtin_amdgcn_global_load_lds(
            (const __attribute__((address_space(1))) void*)(csrc + (size_t)idx * 8),
            (__attribute__((address_space(3))) void*)(&Cs[g][cur ^ 1][0] + (size_t)idx * 8), 16, 0, 0);
      }
    }
    f32x4 acc[4];
    #pragma unroll
    for (int j = 0; j < 4; ++j) acc[j] = (f32x4){0.f, 0.f, 0.f, 0.f};
    #pragma unroll
    for (int kk = 0; kk < 4; ++kk) {
      #pragma unroll
      for (int j = 0; j < 4; ++j) {
        int mrow = j * 16 + rl;
        f16x8 a = *(const f16x8*)(&Cs[g][cur][0] + mrow * 128 + ((kk * 4 + kg) ^ (rl & 7)) * 8);
        acc[j] = __builtin_amdgcn_mfma_f32_16x16x32_f16(a, bq[kk], acc[j], 0, 0, 0);
      }
    }
    // scan 16 scores: key pack, key>gate (gate = max(lane l15, query 32nd bound))
    int cnt = 0;
    int kb = 4095 - (g * 2048 + cb * 64 + kg * 4);
    #pragma unroll
    for (int j = 0; j < 4; ++j) {
      #pragma unroll
      for (int rg = 0; rg < 4; ++rg) {
        float v = fmaxf(acc[j][rg], 0.0f);
        unsigned key = ((unsigned)f2h_bits(v) << 16) | (unsigned)(kb - j * 16 - rg);
        if (key > gate) {
          stk[cnt * 512 + tid] = key;
          ++cnt;
        }
      }
    }
    // prefetched drain, ballot-terminated; gate update only if inserts happened
    if (__ballot(cnt > 0) != 0ull) {
      unsigned nxt = stk[tid];
      for (int i = 0;; ++i) {
        if (__ballot(i < cnt) == 0ull) break;
        unsigned c = (i < cnt) ? nxt : 0u;
        nxt = stk[(unsigned)min(i + 1, 15) * 512 + tid];
        INS16(c);
      }
      unsigned m7 = min(l7, (unsigned)__shfl_xor((int)l7, 16, 64));
      m7 = min(m7, (unsigned)__shfl_xor((int)m7, 32, 64));
      gate = max(l15, m7);
    }
    asm volatile("s_waitcnt vmcnt(0)" ::: "memory");
    __syncthreads();
  }

  // group 1 dumps its sorted lists; group 0 merges in-register + partner list
  if (g == 1) {
    unsigned* dst = stk + (((wq * 16 + rl) * 4 + kg) * 16);
    *(uint4*)(dst + 0)  = (uint4){l0, l1, l2, l3};
    *(uint4*)(dst + 4)  = (uint4){l4, l5, l6, l7};
    *(uint4*)(dst + 8)  = (uint4){l8, l9, l10, l11};
    *(uint4*)(dst + 12) = (uint4){l12, l13, l14, l15};
  }
  __syncthreads();
  if (g == 0) {
    const unsigned* src = stk + (((wq * 16 + rl) * 4 + kg) * 16);
    uint4 pa = *(const uint4*)(src + 0);
    uint4 pb = *(const uint4*)(src + 4);
    uint4 pc = *(const uint4*)(src + 8);
    uint4 pd = *(const uint4*)(src + 12);
    unsigned p0 = pa.x, p1 = pa.y, p2 = pa.z, p3 = pa.w;
    unsigned p4 = pb.x, p5 = pb.y, p6 = pb.z, p7 = pb.w;
    unsigned p8 = pc.x, p9 = pc.y, p10 = pc.z, p11 = pc.w;
    unsigned p12 = pd.x, p13 = pd.y, p14 = pd.z, p15 = pd.w;

    unsigned sv[8];
    float sum = 0.0f;
    #pragma unroll
    for (int e = 0; e < 32; ++e) {
      unsigned v = max(l0, p0);
      v = max(v, (unsigned)__shfl_xor((int)v, 16, 64));
      v = max(v, (unsigned)__shfl_xor((int)v, 32, 64));
      if (l0 == v) { SHIFT_L(); }
      else if (p0 == v) { SHIFT_P(); }
      sum += h2f_bits(v >> 16);
      if (kg == (e & 3)) sv[e >> 2] = v;
    }
    int grow = b * NN + qbase + qrow;
    #pragma unroll
    for (int s = 0; s < 8; ++s) {
      unsigned v = sv[s];
      nidx[(size_t)grow * 32 + s * 4 + kg] = 4095 - (int)(v & 0xFFFu);
      nval[(size_t)grow * 32 + s * 4 + kg] = h2f_bits(v >> 16);
    }
    if (kg == 0) {
      float tau = fmaxf(expf(p_log_tau[0]), 1e-3f);
      float deg = fmaxf(0.9f * ((sum + 1.0f) / tau) + 0.1f, 1e-6f);
      dm12[grow] = 1.0f / sqrtf(deg);
    }
  }
}

// ---- k_cheb1: T1 = Ahat @ h (fp16 gather in, fp16 swizzled out) --------------
__global__ __launch_bounds__(128) void k_cheb1(
    const _Float16* __restrict__ h16, const int* __restrict__ nidx,
    const float* __restrict__ nval, const float* __restrict__ dm12,
    const float* __restrict__ p_log_tau, _Float16* __restrict__ T116) {
  int row = blockIdx.x;
  int b = row >> 12;
  int tid = threadIdx.x;
  __shared__ float cj[32];
  __shared__ int mj[32];
  __shared__ float cdsh;
  float tau = fmaxf(expf(p_log_tau[0]), 1e-3f);
  float scale = 0.9f / tau;
  float dn = dm12[row];
  if (tid < 32) {
    int m = nidx[(size_t)row * 32 + tid];
    cj[tid] = scale * nval[(size_t)row * 32 + tid] * dn * dm12[b * NN + m];
    mj[tid] = m;
  }
  if (tid == 0) cdsh = (scale + 0.1f) * dn * dn;
  __syncthreads();
  int c = tid >> 3, e = tid & 7;
  const _Float16* hb = h16 + (size_t)b * NN * 128;
  float acc = cdsh * (float)h16[(size_t)row * 128 + ((c ^ (row & 7)) << 3) + e];
  #pragma unroll 8
  for (int j = 0; j < 32; ++j) {
    int m = mj[j];
    acc += cj[j] * (float)hb[(size_t)m * 128 + ((c ^ (m & 7)) << 3) + e];
  }
  float p = __shfl_xor(acc, 1, 64);
  if (!(tid & 1))
    *(unsigned*)(T116 + (size_t)row * 128 + ((c ^ (row & 7)) << 3) + e) = pack2h(acc, p);
}

// ---- k_out (FUSED cheb2): stage h/T1 + w2; compute T2 in-block (gather T1
//      from L2); then out = x + tanh(gate)*([h|T1|T2] @ w2 + b2). -------------
__global__ __launch_bounds__(256, 1) void k_out(
    const float* __restrict__ x, const _Float16* __restrict__ h16,
    const _Float16* __restrict__ T116, const _Float16* __restrict__ w2t16,
    const float* __restrict__ b2, const int* __restrict__ nidx,
    const float* __restrict__ nval, const float* __restrict__ dm12,
    const float* __restrict__ p_log_tau, const float* __restrict__ p_gate,
    float* __restrict__ out) {
  __shared__ _Float16 As3[3][64 * 128];     // 48 KB
  __shared__ _Float16 Bs3[3][128 * 128];    // 96 KB
  __shared__ float cjs[64][32];             // 8 KB
  __shared__ unsigned short mjs[64][32];    // 4 KB
  __shared__ float cds[64];
  int tid = threadIdx.x;
  int lane = tid & 63;
  int wv = tid >> 6;
  int rbase = blockIdx.x * 64;
  int b = rbase >> 12;
  // stage h16, T116 rows + all w2 chunks
  const _Float16* srcs[2] = {h16, T116};
  #pragma unroll
  for (int kc = 0; kc < 2; ++kc) {
    const _Float16* src = srcs[kc] + (size_t)rbase * 128;
    #pragma unroll
    for (int i = 0; i < 4; ++i) {
      int idx = tid + 256 * i;
      __builtin_amdgcn_global_load_lds(
          (const __attribute__((address_space(1))) void*)(src + (size_t)idx * 8),
          (__attribute__((address_space(3))) void*)(As3[kc] + (size_t)idx * 8), 16, 0, 0);
    }
  }
  #pragma unroll
  for (int kc = 0; kc < 3; ++kc) {
    #pragma unroll
    for (int i = 0; i < 8; ++i) {
      int idx = tid + 256 * i;
      int n = idx >> 4, cp = idx & 15;
      __builtin_amdgcn_global_load_lds(
          (const __attribute__((address_space(1))) void*)(w2t16 + (size_t)n * 384 + kc * 128 + (size_t)cp * 8),
          (__attribute__((address_space(3))) void*)(Bs3[kc] + (size_t)idx * 8), 16, 0, 0);
    }
  }
  // fill cj/mj/cds for the block's 64 rows
  float tau = fmaxf(expf(p_log_tau[0]), 1e-3f);
  float scale = 0.9f / tau;
  #pragma unroll
  for (int i = 0; i < 8; ++i) {
    int idx = tid + 256 * i;
    int row = idx >> 5, j = idx & 31;
    int grow = rbase + row;
    int m = nidx[(size_t)grow * 32 + j];
    float dn = dm12[grow];
    cjs[row][j] = scale * nval[(size_t)grow * 32 + j] * dn * dm12[b * NN + m];
    mjs[row][j] = (unsigned short)m;
    if (j == 0) cds[row] = (scale + 0.1f) * dn * dn;
  }
  asm volatile("s_waitcnt vmcnt(0)" ::: "memory");
  __syncthreads();

  // compute T2 for own rows into As3[2]: 4 rows x 64 elem-pairs per pass
  const _Float16* T1g = T116 + (size_t)b * NN * 128;
  #pragma unroll 2
  for (int p = 0; p < 16; ++p) {
    int r = p * 4 + (tid >> 6);
    int e0 = (tid & 63) * 2;
    int c0 = e0 >> 3;
    int own = r * 128 + ((c0 ^ (r & 7)) << 3) + (e0 & 7);
    float acc0 = cds[r] * (float)As3[1][own];
    float acc1 = cds[r] * (float)As3[1][own + 1];
    #pragma unroll 8
    for (int j = 0; j < 32; ++j) {
      int m = mjs[r][j];
      float cj = cjs[r][j];
      unsigned u = *(const unsigned*)(T1g + (size_t)m * 128 + ((c0 ^ (m & 7)) << 3) + (e0 & 7));
      acc0 += cj * h2f_bits(u & 0xFFFFu);
      acc1 += cj * h2f_bits(u >> 16);
    }
    float t2a = 2.0f * acc0 - (float)As3[0][own];
    float t2b = 2.0f * acc1 - (float)As3[0][own + 1];
    *(unsigned*)(&As3[2][own]) = pack2h(t2a, t2b);
  }
  __syncthreads();

  int rl = lane & 15, kg = lane >> 4;
  f32x4 acc[8];
  #pragma unroll
  for (int j = 0; j < 8; ++j) acc[j] = (f32x4){0.f, 0.f, 0.f, 0.f};
  #pragma unroll
  for (int kc = 0; kc < 3; ++kc) {
    #pragma unroll
    for (int kk = 0; kk < 4; ++kk) {
      int cL = kk * 4 + kg;
      int r = wv * 16 + rl;
      f16x8 a = *(const f16x8*)(As3[kc] + r * 128 + (cL ^ (r & 7)) * 8);
      #pragma unroll
      for (int j = 0; j < 8; ++j) {
        int n = j * 16 + rl;
        f16x8 bf = *(const f16x8*)(Bs3[kc] + n * 128 + (cL ^ (n & 7)) * 8);
        acc[j] = __builtin_amdgcn_mfma_f32_16x16x32_f16(a, bf, acc[j], 0, 0, 0);
      }
    }
  }
  float tg = tanhf(p_gate[0]);
  #pragma unroll
  for (int j = 0; j < 8; ++j) {
    int col = j * 16 + rl;
    float bv = b2[col];
    #pragma unroll
    for (int rg = 0; rg < 4; ++rg) {
      int row = rbase + wv * 16 + kg * 4 + rg;
      out[(size_t)row * 128 + col] =
          x[(size_t)row * 128 + col] + tg * (acc[j][rg] + bv);
    }
  }
}

extern "C" void kernel_launch(void* const* d_in, const int* in_sizes, int n_in,
                              void* d_out, int out_size, void* d_ws, size_t ws_size,
                              hipStream_t stream) {
  (void)in_sizes; (void)n_in; (void)out_size; (void)ws_size;
  const float* x = (const float*)d_in[0];
  const float* ln_g = (const float*)d_in[1];
  const float* ln_b = (const float*)d_in[2];
  const float* w1 = (const float*)d_in[3];
  const float* b1 = (const float*)d_in[4];
  const float* w2 = (const float*)d_in[5];
  const float* b2 = (const float*)d_in[6];
  const float* p_log_tau = (const float*)d_in[7];
  const float* p_gate = (const float*)d_in[8];
  float* out = (float*)d_out;

  char* ws = (char*)d_ws;
  size_t off = 0;
  auto alloc = [&](size_t bytes) -> void* {
    off = (off + 255) & ~(size_t)255;
    void* p = ws + off;
    off += bytes;
    return p;
  };
  _Float16* h16 = (_Float16*)alloc((size_t)NB * NN * 128 * 2);
  _Float16* hn16 = (_Float16*)alloc((size_t)NB * NN * 128 * 2);
  _Float16* T116 = (_Float16*)alloc((size_t)NB * NN * 128 * 2);
  _Float16* w1t16 = (_Float16*)alloc((size_t)128 * 128 * 2);
  _Float16* w2t16 = (_Float16*)alloc((size_t)128 * 384 * 2);
  int* nidx = (int*)alloc((size_t)NB * NN * 32 * 4);
  float* nval = (float*)alloc((size_t)NB * NN * 32 * 4);
  float* dm12 = (float*)alloc((size_t)NB * NN * 4);

  k_prepw<<<128, 128, 0, stream>>>(w1, w2, w1t16, w2t16);
  k1_mfma<<<NB * NN / 64, 256, 0, stream>>>(x, ln_g, ln_b, w1t16, b1, h16, hn16);
  k_scores_topk<<<NB * 64, 512, 0, stream>>>(hn16, nidx, nval, dm12, p_log_tau);
  k_cheb1<<<NB * NN, 128, 0, stream>>>(h16, nidx, nval, dm12, p_log_tau, T116);
  k_out<<<NB * NN / 64, 256, 0, stream>>>(x, h16, T116, w2t16, b2, nidx, nval,
                                          dm12, p_log_tau, p_gate, out);
}

// Round 13
// 170.437 us; speedup vs baseline: 1.0807x; 1.0807x over previous
//
#include <hip/hip_runtime.h>
#include <hip/hip_bf16.h>
#include <stdint.h>

#define NB 4
#define NN 4096

using f16x8 = __attribute__((ext_vector_type(8))) _Float16;
using f32x4 = __attribute__((ext_vector_type(4))) float;

__device__ __forceinline__ float wave_sum(float v) {
  #pragma unroll
  for (int o = 32; o > 0; o >>= 1) v += __shfl_xor(v, o, 64);
  return v;
}
__device__ __forceinline__ float h2f_bits(unsigned hb) {
  unsigned short us = (unsigned short)hb;
  _Float16 hf;
  __builtin_memcpy(&hf, &us, 2);
  return (float)hf;
}
__device__ __forceinline__ unsigned short f2h_bits(float f) {
  _Float16 hf = (_Float16)f;
  unsigned short us;
  __builtin_memcpy(&us, &hf, 2);
  return us;
}
__device__ __forceinline__ unsigned pack2h(float lo, float hi) {
  return ((unsigned)f2h_bits(hi) << 16) | (unsigned)f2h_bits(lo);
}

// 16-deep branchless sorted-insert cascade (desc). c is clobbered.
#define INS16(c) do { unsigned t_;                      \
  t_ = max(l0, c);  c = min(l0, c);  l0 = t_;           \
  t_ = max(l1, c);  c = min(l1, c);  l1 = t_;           \
  t_ = max(l2, c);  c = min(l2, c);  l2 = t_;           \
  t_ = max(l3, c);  c = min(l3, c);  l3 = t_;           \
  t_ = max(l4, c);  c = min(l4, c);  l4 = t_;           \
  t_ = max(l5, c);  c = min(l5, c);  l5 = t_;           \
  t_ = max(l6, c);  c = min(l6, c);  l6 = t_;           \
  t_ = max(l7, c);  c = min(l7, c);  l7 = t_;           \
  t_ = max(l8, c);  c = min(l8, c);  l8 = t_;           \
  t_ = max(l9, c);  c = min(l9, c);  l9 = t_;           \
  t_ = max(l10, c); c = min(l10, c); l10 = t_;          \
  t_ = max(l11, c); c = min(l11, c); l11 = t_;          \
  t_ = max(l12, c); c = min(l12, c); l12 = t_;          \
  t_ = max(l13, c); c = min(l13, c); l13 = t_;          \
  t_ = max(l14, c); c = min(l14, c); l14 = t_;          \
  l15 = max(l15, c);                                    \
} while (0)

#define SHIFT_L() do { l0=l1; l1=l2; l2=l3; l3=l4; l4=l5; l5=l6; l6=l7; l7=l8; \
  l8=l9; l9=l10; l10=l11; l11=l12; l12=l13; l13=l14; l14=l15; l15=0; } while (0)
#define SHIFT_P() do { p0=p1; p1=p2; p2=p3; p3=p4; p4=p5; p5=p6; p6=p7; p7=p8; \
  p8=p9; p9=p10; p10=p11; p11=p12; p12=p13; p13=p14; p14=p15; p15=0; } while (0)

// ---- k_prepw: fused weight transpose+fp16 pack (w1 and w2), swizzled ---------
__global__ __launch_bounds__(128) void k_prepw(
    const float* __restrict__ w1, const float* __restrict__ w2,
    _Float16* __restrict__ w1t16, _Float16* __restrict__ w2t16) {
  int n = blockIdx.x;
  int t = threadIdx.x;
  __shared__ _Float16 v16[128];
  __shared__ float v[384];
  v16[t] = (_Float16)w1[(size_t)t * 128 + n];
  #pragma unroll
  for (int i = 0; i < 3; ++i) v[i * 128 + t] = w2[(size_t)(i * 128 + t) * 128 + n];
  __syncthreads();
  if (t < 16) {
    union { _Float16 hh[8]; uint4 u; } pk;
    #pragma unroll
    for (int j = 0; j < 8; ++j) pk.hh[j] = v16[t * 8 + j];
    *(uint4*)(w1t16 + (size_t)n * 128 + (size_t)(t ^ (n & 7)) * 8) = pk.u;
  }
  if (t < 48) {
    int kc = t >> 4, cl = t & 15;
    union { _Float16 hh[8]; uint4 u; } pk;
    #pragma unroll
    for (int e = 0; e < 8; ++e) pk.hh[e] = (_Float16)v[t * 8 + e];
    *(uint4*)(w2t16 + (size_t)n * 384 + kc * 128 + (size_t)(cl ^ (n & 7)) * 8) = pk.u;
  }
}

// ---- k0_ln: wave-per-row LayerNorm -> ln16 (fp16, swizzled), no barriers -----
__global__ __launch_bounds__(256) void k0_ln(
    const float* __restrict__ x, const float* __restrict__ ln_g,
    const float* __restrict__ ln_b, _Float16* __restrict__ ln16) {
  int lane = threadIdx.x & 63;
  int row = blockIdx.x * 4 + (threadIdx.x >> 6);
  float2 xv = ((const float2*)x)[(size_t)row * 64 + lane];
  float2 gv = ((const float2*)ln_g)[lane];
  float2 bv = ((const float2*)ln_b)[lane];
  float mu = wave_sum(xv.x + xv.y) * (1.0f / 128.0f);
  float dx = xv.x - mu, dy = xv.y - mu;
  float var = wave_sum(dx * dx + dy * dy) * (1.0f / 128.0f);
  float ri = 1.0f / sqrtf(var + 1e-5f);
  float h0 = dx * ri * gv.x + bv.x;
  float h1 = dy * ri * gv.y + bv.y;
  int c = lane >> 2;
  int addr = row * 128 + ((c ^ (row & 7)) << 3) + (lane & 3) * 2;
  *(unsigned*)(ln16 + addr) = pack2h(h0, h1);
}

// ---- k1_mfma: h = GELU(ln @ w1 + b1); writes h16 + hn16 (normalized) ---------
__global__ __launch_bounds__(256) void k1_mfma(
    const _Float16* __restrict__ ln16, const _Float16* __restrict__ w1t16,
    const float* __restrict__ b1, _Float16* __restrict__ h16,
    _Float16* __restrict__ hn16) {
  __shared__ _Float16 As[64 * 128];
  __shared__ _Float16 Bs[128 * 128];
  int tid = threadIdx.x;
  int lane = tid & 63;
  int wv = tid >> 6;
  int rbase = blockIdx.x * 64;
  #pragma unroll
  for (int i = 0; i < 4; ++i) {
    int idx = tid + 256 * i;
    __builtin_amdgcn_global_load_lds(
        (const __attribute__((address_space(1))) void*)(ln16 + (size_t)rbase * 128 + (size_t)idx * 8),
        (__attribute__((address_space(3))) void*)(As + (size_t)idx * 8), 16, 0, 0);
  }
  #pragma unroll
  for (int i = 0; i < 8; ++i) {
    int idx = tid + 256 * i;
    __builtin_amdgcn_global_load_lds(
        (const __attribute__((address_space(1))) void*)(w1t16 + (size_t)idx * 8),
        (__attribute__((address_space(3))) void*)(Bs + (size_t)idx * 8), 16, 0, 0);
  }
  asm volatile("s_waitcnt vmcnt(0)" ::: "memory");
  __syncthreads();

  int rl = lane & 15, kg = lane >> 4;
  f32x4 acc[8];
  #pragma unroll
  for (int j = 0; j < 8; ++j) acc[j] = (f32x4){0.f, 0.f, 0.f, 0.f};
  #pragma unroll
  for (int kk = 0; kk < 4; ++kk) {
    int cL = kk * 4 + kg;
    int r = wv * 16 + rl;
    f16x8 a = *(const f16x8*)(As + r * 128 + (cL ^ (r & 7)) * 8);
    #pragma unroll
    for (int j = 0; j < 8; ++j) {
      int n = j * 16 + rl;
      f16x8 bf = *(const f16x8*)(Bs + n * 128 + (cL ^ (n & 7)) * 8);
      acc[j] = __builtin_amdgcn_mfma_f32_16x16x32_f16(a, bf, acc[j], 0, 0, 0);
    }
  }
  float ssq[4] = {0.f, 0.f, 0.f, 0.f};
  #pragma unroll
  for (int j = 0; j < 8; ++j) {
    float bv = b1[j * 16 + rl];
    #pragma unroll
    for (int rg = 0; rg < 4; ++rg) {
      float z = acc[j][rg] + bv;
      float g = 0.5f * z * (1.0f + erff(z * 0.70710678118654752440f));
      acc[j][rg] = g;
      ssq[rg] += g * g;
    }
  }
  #pragma unroll
  for (int o = 1; o < 16; o <<= 1)
    #pragma unroll
    for (int rg = 0; rg < 4; ++rg) ssq[rg] += __shfl_xor(ssq[rg], o, 64);
  float rinv[4];
  #pragma unroll
  for (int rg = 0; rg < 4; ++rg) rinv[rg] = 1.0f / fmaxf(sqrtf(ssq[rg]), 1e-12f);

  #pragma unroll
  for (int j = 0; j < 8; ++j) {
    #pragma unroll
    for (int rg = 0; rg < 4; ++rg) {
      float g = acc[j][rg];
      float gp = __shfl_xor(g, 1, 64);
      if ((rl & 1) == 0) {
        int row = rbase + wv * 16 + kg * 4 + rg;
        int col = j * 16 + rl;
        int c = col >> 3;
        int ad = row * 128 + (((c ^ (row & 7))) << 3) + (col & 7);
        *(unsigned*)(h16 + ad) = pack2h(g, gp);
        *(unsigned*)(hn16 + ad) = pack2h(g * rinv[rg], gp * rinv[rg]);
      }
    }
  }
}

// ---- k_scores_topk v6: 512 thr, 8 waves, m-halves; exact global-top32 gate
//      (min-of-l7 across kg lanes) + shfl-wm prefetched drain. ----------------
__global__ __launch_bounds__(512, 1) void k_scores_topk(
    const _Float16* __restrict__ hn16, int* __restrict__ nidx,
    float* __restrict__ nval, float* __restrict__ dm12,
    const float* __restrict__ p_log_tau) {
  __shared__ _Float16 Qs[64 * 128];         // 16 KB
  __shared__ _Float16 Cs[2][2][64 * 128];   // 64 KB: [group][dbuf]
  __shared__ unsigned stk[16 * 512];        // 32 KB: stacks, then merge buffer
  int tid = threadIdx.x;
  int lane = tid & 63;
  int wv = tid >> 6;            // 0..7
  int g = wv >> 2;              // m-half
  int wq = wv & 3;
  int rl = lane & 15, kg = lane >> 4;
  int t = tid & 255;            // group-local tid
  int blk = blockIdx.x;
  int b = blk >> 6;
  int qbase = (blk & 63) * 64;
  const _Float16* hb = hn16 + (size_t)b * NN * 128;

  #pragma unroll
  for (int i = 0; i < 2; ++i) {
    int idx = tid + 512 * i;
    __builtin_amdgcn_global_load_lds(
        (const __attribute__((address_space(1))) void*)(hb + (size_t)qbase * 128 + (size_t)idx * 8),
        (__attribute__((address_space(3))) void*)(Qs + (size_t)idx * 8), 16, 0, 0);
  }
  const _Float16* cw = hb + (size_t)(g * 2048) * 128;
  #pragma unroll
  for (int i = 0; i < 4; ++i) {
    int idx = t + 256 * i;
    __builtin_amdgcn_global_load_lds(
        (const __attribute__((address_space(1))) void*)(cw + (size_t)idx * 8),
        (__attribute__((address_space(3))) void*)(&Cs[g][0][0] + (size_t)idx * 8), 16, 0, 0);
  }
  asm volatile("s_waitcnt vmcnt(0)" ::: "memory");
  __syncthreads();

  int qrow = wq * 16 + rl;
  f16x8 bq[4];
  #pragma unroll
  for (int kk = 0; kk < 4; ++kk)
    bq[kk] = *(const f16x8*)(Qs + qrow * 128 + ((kk * 4 + kg) ^ (qrow & 7)) * 8);

  unsigned l0 = 0, l1 = 0, l2 = 0, l3 = 0, l4 = 0, l5 = 0, l6 = 0, l7 = 0,
           l8 = 0, l9 = 0, l10 = 0, l11 = 0, l12 = 0, l13 = 0, l14 = 0, l15 = 0;
  unsigned gate = 0;

  for (int cb = 0; cb < 32; ++cb) {
    int cur = cb & 1;
    if (cb < 31) {  // prefetch next private-group tile
      const _Float16* csrc = cw + (size_t)(cb + 1) * 64 * 128;
      #pragma unroll
      for (int i = 0; i < 4; ++i) {
        int idx = t + 256 * i;
        __builtin_amdgcn_global_load_lds(
            (const __attribute__((address_space(1))) void*)(csrc + (size_t)idx * 8),
            (__attribute__((address_space(3))) void*)(&Cs[g][cur ^ 1][0] + (size_t)idx * 8), 16, 0, 0);
      }
    }
    f32x4 acc[4];
    #pragma unroll
    for (int j = 0; j < 4; ++j) acc[j] = (f32x4){0.f, 0.f, 0.f, 0.f};
    #pragma unroll
    for (int kk = 0; kk < 4; ++kk) {
      #pragma unroll
      for (int j = 0; j < 4; ++j) {
        int mrow = j * 16 + rl;
        f16x8 a = *(const f16x8*)(&Cs[g][cur][0] + mrow * 128 + ((kk * 4 + kg) ^ (rl & 7)) * 8);
        acc[j] = __builtin_amdgcn_mfma_f32_16x16x32_f16(a, bq[kk], acc[j], 0, 0, 0);
      }
    }
    // scan 16 scores: key pack, key>gate (gate = max(lane l15, query 32nd bound))
    int cnt = 0;
    int kb = 4095 - (g * 2048 + cb * 64 + kg * 4);
    #pragma unroll
    for (int j = 0; j < 4; ++j) {
      #pragma unroll
      for (int rg = 0; rg < 4; ++rg) {
        float v = fmaxf(acc[j][rg], 0.0f);
        unsigned key = ((unsigned)f2h_bits(v) << 16) | (unsigned)(kb - j * 16 - rg);
        if (key > gate) {
          stk[cnt * 512 + tid] = key;
          ++cnt;
        }
      }
    }
    // prefetched drain: wave-max count, pipeline stack reads past INS16 chain
    int wm = cnt;
    #pragma unroll
    for (int o = 1; o < 64; o <<= 1) {
      int w = __shfl_xor(wm, o, 64);
      wm = max(wm, w);
    }
    if (wm > 0) {
      unsigned nxt = stk[tid];
      for (int i = 0; i < wm; ++i) {
        unsigned c = (i < cnt) ? nxt : 0u;
        nxt = stk[(unsigned)min(i + 1, 15) * 512 + tid];
        INS16(c);
      }
      // exact query-global 32nd-best bound: min of l7 across the 4 kg lanes
      unsigned m7 = min(l7, (unsigned)__shfl_xor((int)l7, 16, 64));
      m7 = min(m7, (unsigned)__shfl_xor((int)m7, 32, 64));
      gate = max(l15, m7);
    }
    asm volatile("s_waitcnt vmcnt(0)" ::: "memory");
    __syncthreads();
  }

  // group 1 dumps its sorted lists; group 0 merges in-register + partner list
  if (g == 1) {
    unsigned* dst = stk + (((wq * 16 + rl) * 4 + kg) * 16);
    *(uint4*)(dst + 0)  = (uint4){l0, l1, l2, l3};
    *(uint4*)(dst + 4)  = (uint4){l4, l5, l6, l7};
    *(uint4*)(dst + 8)  = (uint4){l8, l9, l10, l11};
    *(uint4*)(dst + 12) = (uint4){l12, l13, l14, l15};
  }
  __syncthreads();
  if (g == 0) {
    const unsigned* src = stk + (((wq * 16 + rl) * 4 + kg) * 16);
    uint4 pa = *(const uint4*)(src + 0);
    uint4 pb = *(const uint4*)(src + 4);
    uint4 pc = *(const uint4*)(src + 8);
    uint4 pd = *(const uint4*)(src + 12);
    unsigned p0 = pa.x, p1 = pa.y, p2 = pa.z, p3 = pa.w;
    unsigned p4 = pb.x, p5 = pb.y, p6 = pb.z, p7 = pb.w;
    unsigned p8 = pc.x, p9 = pc.y, p10 = pc.z, p11 = pc.w;
    unsigned p12 = pd.x, p13 = pd.y, p14 = pd.z, p15 = pd.w;

    unsigned sv[8];
    float sum = 0.0f;
    #pragma unroll
    for (int e = 0; e < 32; ++e) {
      unsigned v = max(l0, p0);
      v = max(v, (unsigned)__shfl_xor((int)v, 16, 64));
      v = max(v, (unsigned)__shfl_xor((int)v, 32, 64));
      if (l0 == v) { SHIFT_L(); }
      else if (p0 == v) { SHIFT_P(); }
      sum += h2f_bits(v >> 16);
      if (kg == (e & 3)) sv[e >> 2] = v;
    }
    int grow = b * NN + qbase + qrow;
    #pragma unroll
    for (int s = 0; s < 8; ++s) {
      unsigned v = sv[s];
      nidx[(size_t)grow * 32 + s * 4 + kg] = 4095 - (int)(v & 0xFFFu);
      nval[(size_t)grow * 32 + s * 4 + kg] = h2f_bits(v >> 16);
    }
    if (kg == 0) {
      float tau = fmaxf(expf(p_log_tau[0]), 1e-3f);
      float deg = fmaxf(0.9f * ((sum + 1.0f) / tau) + 0.1f, 1e-6f);
      dm12[grow] = 1.0f / sqrtf(deg);
    }
  }
}

// ---- k_cheb1: T1 = Ahat @ h (fp16 gather in, fp16 swizzled out) --------------
__global__ __launch_bounds__(128) void k_cheb1(
    const _Float16* __restrict__ h16, const int* __restrict__ nidx,
    const float* __restrict__ nval, const float* __restrict__ dm12,
    const float* __restrict__ p_log_tau, _Float16* __restrict__ T116) {
  int row = blockIdx.x;
  int b = row >> 12;
  int tid = threadIdx.x;
  __shared__ float cj[32];
  __shared__ int mj[32];
  __shared__ float cdsh;
  float tau = fmaxf(expf(p_log_tau[0]), 1e-3f);
  float scale = 0.9f / tau;
  float dn = dm12[row];
  if (tid < 32) {
    int m = nidx[(size_t)row * 32 + tid];
    cj[tid] = scale * nval[(size_t)row * 32 + tid] * dn * dm12[b * NN + m];
    mj[tid] = m;
  }
  if (tid == 0) cdsh = (scale + 0.1f) * dn * dn;
  __syncthreads();
  int c = tid >> 3, e = tid & 7;
  const _Float16* hb = h16 + (size_t)b * NN * 128;
  float acc = cdsh * (float)h16[(size_t)row * 128 + ((c ^ (row & 7)) << 3) + e];
  #pragma unroll 8
  for (int j = 0; j < 32; ++j) {
    int m = mj[j];
    acc += cj[j] * (float)hb[(size_t)m * 128 + ((c ^ (m & 7)) << 3) + e];
  }
  float p = __shfl_xor(acc, 1, 64);
  if (!(tid & 1))
    *(unsigned*)(T116 + (size_t)row * 128 + ((c ^ (row & 7)) << 3) + e) = pack2h(acc, p);
}

// ---- k_cheb2: T2 = 2*Ahat@T1 - h (fp16 in/out) -------------------------------
__global__ __launch_bounds__(128) void k_cheb2(
    const _Float16* __restrict__ h16, const _Float16* __restrict__ T116,
    const int* __restrict__ nidx, const float* __restrict__ nval,
    const float* __restrict__ dm12, const float* __restrict__ p_log_tau,
    _Float16* __restrict__ T216) {
  int row = blockIdx.x;
  int b = row >> 12;
  int tid = threadIdx.x;
  __shared__ float cj[32];
  __shared__ int mj[32];
  __shared__ float cdsh;
  float tau = fmaxf(expf(p_log_tau[0]), 1e-3f);
  float scale = 0.9f / tau;
  float dn = dm12[row];
  if (tid < 32) {
    int m = nidx[(size_t)row * 32 + tid];
    cj[tid] = scale * nval[(size_t)row * 32 + tid] * dn * dm12[b * NN + m];
    mj[tid] = m;
  }
  if (tid == 0) cdsh = (scale + 0.1f) * dn * dn;
  __syncthreads();
  int c = tid >> 3, e = tid & 7;
  int sw_own = ((c ^ (row & 7)) << 3) + e;
  const _Float16* T1b = T116 + (size_t)b * NN * 128;
  float a = cdsh * (float)T116[(size_t)row * 128 + sw_own];
  #pragma unroll 8
  for (int j = 0; j < 32; ++j) {
    int m = mj[j];
    a += cj[j] * (float)T1b[(size_t)m * 128 + ((c ^ (m & 7)) << 3) + e];
  }
  float t2 = 2.0f * a - (float)h16[(size_t)row * 128 + sw_own];
  float p = __shfl_xor(t2, 1, 64);
  if (!(tid & 1))
    *(unsigned*)(T216 + (size_t)row * 128 + sw_own) = pack2h(t2, p);
}

// ---- k_out: out = x + tanh(gate)*([h|T1|T2] @ w2 + b2); fp16 MFMA ------------
__global__ __launch_bounds__(256, 1) void k_out(
    const float* __restrict__ x, const _Float16* __restrict__ h16,
    const _Float16* __restrict__ T116, const _Float16* __restrict__ T216,
    const _Float16* __restrict__ w2t16, const float* __restrict__ b2,
    const float* __restrict__ p_gate, float* __restrict__ out) {
  __shared__ _Float16 As3[3][64 * 128];
  __shared__ _Float16 Bs3[3][128 * 128];
  int tid = threadIdx.x;
  int lane = tid & 63;
  int wv = tid >> 6;
  int rbase = blockIdx.x * 64;
  const _Float16* srcs[3] = {h16, T116, T216};
  #pragma unroll
  for (int kc = 0; kc < 3; ++kc) {
    const _Float16* src = srcs[kc] + (size_t)rbase * 128;
    #pragma unroll
    for (int i = 0; i < 4; ++i) {
      int idx = tid + 256 * i;
      __builtin_amdgcn_global_load_lds(
          (const __attribute__((address_space(1))) void*)(src + (size_t)idx * 8),
          (__attribute__((address_space(3))) void*)(As3[kc] + (size_t)idx * 8), 16, 0, 0);
    }
    #pragma unroll
    for (int i = 0; i < 8; ++i) {
      int idx = tid + 256 * i;
      int n = idx >> 4, cp = idx & 15;
      __builtin_amdgcn_global_load_lds(
          (const __attribute__((address_space(1))) void*)(w2t16 + (size_t)n * 384 + kc * 128 + (size_t)cp * 8),
          (__attribute__((address_space(3))) void*)(Bs3[kc] + (size_t)idx * 8), 16, 0, 0);
    }
  }
  asm volatile("s_waitcnt vmcnt(0)" ::: "memory");
  __syncthreads();

  int rl = lane & 15, kg = lane >> 4;
  f32x4 acc[8];
  #pragma unroll
  for (int j = 0; j < 8; ++j) acc[j] = (f32x4){0.f, 0.f, 0.f, 0.f};
  #pragma unroll
  for (int kc = 0; kc < 3; ++kc) {
    #pragma unroll
    for (int kk = 0; kk < 4; ++kk) {
      int cL = kk * 4 + kg;
      int r = wv * 16 + rl;
      f16x8 a = *(const f16x8*)(As3[kc] + r * 128 + (cL ^ (r & 7)) * 8);
      #pragma unroll
      for (int j = 0; j < 8; ++j) {
        int n = j * 16 + rl;
        f16x8 bf = *(const f16x8*)(Bs3[kc] + n * 128 + (cL ^ (n & 7)) * 8);
        acc[j] = __builtin_amdgcn_mfma_f32_16x16x32_f16(a, bf, acc[j], 0, 0, 0);
      }
    }
  }
  float tg = tanhf(p_gate[0]);
  #pragma unroll
  for (int j = 0; j < 8; ++j) {
    int col = j * 16 + rl;
    float bv = b2[col];
    #pragma unroll
    for (int rg = 0; rg < 4; ++rg) {
      int row = rbase + wv * 16 + kg * 4 + rg;
      out[(size_t)row * 128 + col] =
          x[(size_t)row * 128 + col] + tg * (acc[j][rg] + bv);
    }
  }
}

extern "C" void kernel_launch(void* const* d_in, const int* in_sizes, int n_in,
                              void* d_out, int out_size, void* d_ws, size_t ws_size,
                              hipStream_t stream) {
  (void)in_sizes; (void)n_in; (void)out_size; (void)ws_size;
  const float* x = (const float*)d_in[0];
  const float* ln_g = (const float*)d_in[1];
  const float* ln_b = (const float*)d_in[2];
  const float* w1 = (const float*)d_in[3];
  const float* b1 = (const float*)d_in[4];
  const float* w2 = (const float*)d_in[5];
  const float* b2 = (const float*)d_in[6];
  const float* p_log_tau = (const float*)d_in[7];
  const float* p_gate = (const float*)d_in[8];
  float* out = (float*)d_out;

  char* ws = (char*)d_ws;
  size_t off = 0;
  auto alloc = [&](size_t bytes) -> void* {
    off = (off + 255) & ~(size_t)255;
    void* p = ws + off;
    off += bytes;
    return p;
  };
  _Float16* ln16 = (_Float16*)alloc((size_t)NB * NN * 128 * 2);
  _Float16* h16 = (_Float16*)alloc((size_t)NB * NN * 128 * 2);
  _Float16* hn16 = (_Float16*)alloc((size_t)NB * NN * 128 * 2);
  _Float16* T116 = (_Float16*)alloc((size_t)NB * NN * 128 * 2);
  _Float16* T216 = (_Float16*)alloc((size_t)NB * NN * 128 * 2);
  _Float16* w1t16 = (_Float16*)alloc((size_t)128 * 128 * 2);
  _Float16* w2t16 = (_Float16*)alloc((size_t)128 * 384 * 2);
  int* nidx = (int*)alloc((size_t)NB * NN * 32 * 4);
  float* nval = (float*)alloc((size_t)NB * NN * 32 * 4);
  float* dm12 = (float*)alloc((size_t)NB * NN * 4);

  k_prepw<<<128, 128, 0, stream>>>(w1, w2, w1t16, w2t16);
  k0_ln<<<NB * NN / 4, 256, 0, stream>>>(x, ln_g, ln_b, ln16);
  k1_mfma<<<NB * NN / 64, 256, 0, stream>>>(ln16, w1t16, b1, h16, hn16);
  k_scores_topk<<<NB * 64, 512, 0, stream>>>(hn16, nidx, nval, dm12, p_log_tau);
  k_cheb1<<<NB * NN, 128, 0, stream>>>(h16, nidx, nval, dm12, p_log_tau, T116);
  k_cheb2<<<NB * NN, 128, 0, stream>>>(h16, T116, nidx, nval, dm12, p_log_tau, T216);
  k_out<<<NB * NN / 64, 256, 0, stream>>>(x, h16, T116, T216, w2t16, b2, p_gate, out);
}